// Round 7
// baseline (240.688 us; speedup 1.0000x reference)
//
#include <hip/hip_runtime.h>
#include <hip/hip_fp16.h>

#define N_NODES 65536
#define N_EDGES 1048576
#define F_IN    16
#define H       64
#define N_GRAPHS 32
#define NPG     2048
#define OUT_F   12
#define KPG     (NPG * H)   // 131072 per-graph K for FC

// ================================================================ CSR build
// Edges pack into uint32: src (16b) | dst (16b) << 16.
// Bucket = dst>>8 (256 buckets of 256 nodes). Two-level LDS counting sort.

// 256 blocks x 4096 edges: per-block histogram -> blockHist[blk][bucket] (no atomics/memset)
__global__ __launch_bounds__(256) void bucket_count_kernel(const int* __restrict__ dst,
                                                           int* __restrict__ blockHist) {
    __shared__ int h[256];
    int t = threadIdx.x;
    h[t] = 0;
    __syncthreads();
    int base = blockIdx.x * 4096;
#pragma unroll
    for (int i = 0; i < 16; i++) {
        int d = dst[base + i * 256 + t];
        atomicAdd(&h[d >> 8], 1);
    }
    __syncthreads();
    blockHist[blockIdx.x * 256 + t] = h[t];
}

// 1 block: sum per-block hists, scan -> bucketBase[257], init gCursor; bias-init out
__global__ __launch_bounds__(256) void scan_buckets_kernel(const int* __restrict__ blockHist,
                                                           int* __restrict__ bucketBase,
                                                           int* __restrict__ gCursor,
                                                           const float* __restrict__ bfc,
                                                           float* __restrict__ out) {
    int t = threadIdx.x;
    __shared__ int sc[256];
    int c = 0;
    for (int i = 0; i < 256; i++) c += blockHist[i * 256 + t];
    sc[t] = c;
    __syncthreads();
    for (int off = 1; off < 256; off <<= 1) {
        int v = (t >= off) ? sc[t - off] : 0;
        __syncthreads();
        sc[t] += v;
        __syncthreads();
    }
    int excl = sc[t] - c;
    bucketBase[t] = excl;
    gCursor[t]    = excl;
    if (t == 255) bucketBase[256] = N_EDGES;
    for (int i = t; i < N_GRAPHS * OUT_F; i += 256) out[i] = bfc[i % OUT_F];
}

// 256 blocks x 4096 edges: LDS-staged bin by dst>>8, coalesced flush into bucket regions
__global__ __launch_bounds__(256) void binA_kernel(const int* __restrict__ src,
                                                   const int* __restrict__ dst,
                                                   int* __restrict__ gCursor,
                                                   unsigned int* __restrict__ binned) {
    __shared__ int hist[256];
    __shared__ int sc[256];
    __shared__ int bnd[257];
    __shared__ int lcur[256];
    __shared__ int blkBase[256];
    __shared__ unsigned int staged[4096];
    int t = threadIdx.x;
    hist[t] = 0; lcur[t] = 0;
    __syncthreads();
    int e0 = blockIdx.x * 4096;
    unsigned int rec[16];
#pragma unroll
    for (int i = 0; i < 16; i++) {
        int e = e0 + i * 256 + t;
        unsigned int s = (unsigned int)src[e];
        unsigned int d = (unsigned int)dst[e];
        rec[i] = s | (d << 16);
        atomicAdd(&hist[d >> 8], 1);
    }
    __syncthreads();
    int cnt = hist[t];
    if (cnt) blkBase[t] = atomicAdd(&gCursor[t], cnt);
    sc[t] = cnt;
    __syncthreads();
    for (int off = 1; off < 256; off <<= 1) {
        int v = (t >= off) ? sc[t - off] : 0;
        __syncthreads();
        sc[t] += v;
        __syncthreads();
    }
    bnd[t] = sc[t] - cnt;
    if (t == 255) bnd[256] = 4096;
    __syncthreads();
#pragma unroll
    for (int i = 0; i < 16; i++) {
        int b = rec[i] >> 24;
        int p = bnd[b] + atomicAdd(&lcur[b], 1);
        staged[p] = rec[i];
    }
    __syncthreads();
    for (int i = t; i < 4096; i += 256) {
        int lo = 0;
#pragma unroll
        for (int s = 128; s > 0; s >>= 1)
            if (bnd[lo + s] <= i) lo += s;
        binned[blkBase[lo] + (i - bnd[lo])] = staged[i];
    }
}

// block per bucket: counting sort -> nbr (ushort), rowptr, dinv; PLUS fused g1h write
// (this block owns nodes [b*256, b*256+256) and just computed their dinv).
__global__ __launch_bounds__(256) void binB_g1_kernel(const unsigned int* __restrict__ binned,
                                                      const int* __restrict__ bucketBase,
                                                      const float* __restrict__ x,
                                                      int* __restrict__ rowptr,
                                                      float* __restrict__ dinv,
                                                      unsigned short* __restrict__ nbr,
                                                      __half2* __restrict__ g1h) {
    __shared__ int hist[256];
    __shared__ int sc[256];
    __shared__ int off[256];
    __shared__ int cur[256];
    __shared__ unsigned short outS[8192];
    int b = blockIdx.x, t = threadIdx.x;
    int base = bucketBase[b];
    int cnt  = bucketBase[b + 1] - base;
    hist[t] = 0; cur[t] = 0;
    __syncthreads();
    for (int i = t; i < cnt; i += 256) {
        unsigned int r = binned[base + i];
        atomicAdd(&hist[(r >> 16) & 255], 1);
    }
    __syncthreads();
    int c = hist[t];
    sc[t] = c;
    __syncthreads();
    for (int o = 1; o < 256; o <<= 1) {
        int v = (t >= o) ? sc[t - o] : 0;
        __syncthreads();
        sc[t] += v;
        __syncthreads();
    }
    off[t] = sc[t] - c;
    int nd = (b << 8) + t;
    float dv = rsqrtf((float)(c + 1));
    rowptr[nd] = base + sc[t] - c;
    dinv[nd]   = dv;
    if (b == 255 && t == 255) rowptr[N_NODES] = N_EDGES;
    // fused g1: g1h[nd] = fp16(dv * x[nd])
    {
        const float4* xr = (const float4*)(x + (size_t)nd * F_IN);
        float4 x0 = xr[0], x1 = xr[1], x2 = xr[2], x3 = xr[3];
        __half2* gr = g1h + nd * 8;
        gr[0] = __floats2half2_rn(x0.x * dv, x0.y * dv);
        gr[1] = __floats2half2_rn(x0.z * dv, x0.w * dv);
        gr[2] = __floats2half2_rn(x1.x * dv, x1.y * dv);
        gr[3] = __floats2half2_rn(x1.z * dv, x1.w * dv);
        gr[4] = __floats2half2_rn(x2.x * dv, x2.y * dv);
        gr[5] = __floats2half2_rn(x2.z * dv, x2.w * dv);
        gr[6] = __floats2half2_rn(x3.x * dv, x3.y * dv);
        gr[7] = __floats2half2_rn(x3.z * dv, x3.w * dv);
    }
    __syncthreads();
    for (int i = t; i < cnt; i += 256) {
        unsigned int r = binned[base + i];
        int n = (r >> 16) & 255;
        int p = off[n] + atomicAdd(&cur[n], 1);
        outS[p] = (unsigned short)(r & 0xFFFF);
    }
    __syncthreads();
    for (int i = t; i < cnt; i += 256) nbr[base + i] = outS[i];
}

// ================================================================ layer 1 fused
// agg1 (wave per node, 8 edges/round) + gemm1 via shfl broadcast -> g2h directly.
__global__ __launch_bounds__(256) void agg1gemm1_kernel(const __half2* __restrict__ g1h,
                                                        const int* __restrict__ rowptr,
                                                        const unsigned short* __restrict__ nbr,
                                                        const float* __restrict__ dinv,
                                                        const float* __restrict__ W1,
                                                        const float* __restrict__ b1,
                                                        __half* __restrict__ g2h) {
    __shared__ float Ws[F_IN * H];
    __shared__ float bs[H];
    int t = threadIdx.x;
    for (int i = t; i < F_IN * H; i += 256) Ws[i] = W1[i];
    if (t < H) bs[t] = b1[t];
    __syncthreads();
    int lane = t & 63;
    int f2   = lane & 7;
    int sub  = lane >> 3;
    int wid  = blockIdx.x * 4 + (t >> 6);      // [0, 16384)
    for (int v = wid; v < N_NODES; v += 16384) {
        int r0 = rowptr[v], r1 = rowptr[v + 1];
        float ax = 0.f, ay = 0.f;
        for (int base = r0; base < r1; base += 64) {
            int er = min(64, r1 - base);
            int nb = (int)nbr[base + lane];
            int j = 0;
            for (; j + 16 <= er; j += 16) {
                int u0 = __shfl(nb, j + sub, 64);
                int u1 = __shfl(nb, j + 8 + sub, 64);
                float2 x0 = __half22float2(g1h[(u0 << 3) + f2]);
                float2 x1 = __half22float2(g1h[(u1 << 3) + f2]);
                ax += x0.x + x1.x;
                ay += x0.y + x1.y;
            }
            for (; j < er; j += 8) {
                int idx = j + sub;
                int u = __shfl(nb, idx < er ? idx : 0, 64);
                float2 xv = __half22float2(g1h[(u << 3) + f2]);
                if (idx < er) { ax += xv.x; ay += xv.y; }
            }
        }
        // reduce over sub -> ALL lanes hold totals for features (2*f2, 2*f2+1)
        ax += __shfl_xor(ax, 8, 64); ax += __shfl_xor(ax, 16, 64); ax += __shfl_xor(ax, 32, 64);
        ay += __shfl_xor(ay, 8, 64); ay += __shfl_xor(ay, 16, 64); ay += __shfl_xor(ay, 32, 64);
        float dv = dinv[v];
        float2 sv = __half22float2(g1h[(v << 3) + f2]);
        float a1x = dv * (ax + sv.x);
        float a1y = dv * (ay + sv.y);
        // gemm1: s = b1[lane] + sum_k a1[k] * W1[k][lane]; feature pair k from lane k>>1
        float s = bs[lane];
#pragma unroll
        for (int k = 0; k < F_IN; k += 2) {
            float vx = __shfl(a1x, k >> 1, 64);
            float vy = __shfl(a1y, k >> 1, 64);
            s += vx * Ws[k * H + lane] + vy * Ws[(k + 1) * H + lane];
        }
        g2h[(v << 6) + lane] = __float2half(dv * tanhf(s));
    }
}

// ================================================================ layer 2 fused
// agg2 (wave per node, 2 edges/round x4) + gemm2 via shfl broadcast -> h2 directly.
__global__ __launch_bounds__(256) void agg2gemm2_kernel(const __half2* __restrict__ g2h,
                                                        const int* __restrict__ rowptr,
                                                        const unsigned short* __restrict__ nbr,
                                                        const float* __restrict__ dinv,
                                                        const float* __restrict__ W2,
                                                        const float* __restrict__ b2,
                                                        float* __restrict__ h2) {
    __shared__ float Ws[H * H];
    __shared__ float bs[H];
    int t = threadIdx.x;
    for (int i = t; i < H * H; i += 256) Ws[i] = W2[i];
    if (t < H) bs[t] = b2[t];
    __syncthreads();
    int lane = t & 63;
    int f2   = lane & 31;
    int sub  = lane >> 5;
    int wid  = blockIdx.x * 4 + (t >> 6);
    for (int v = wid; v < N_NODES; v += 16384) {
        int r0 = rowptr[v], r1 = rowptr[v + 1];
        float ax = 0.f, ay = 0.f;
        for (int base = r0; base < r1; base += 64) {
            int er = min(64, r1 - base);
            int nb = (int)nbr[base + lane];
            int j = 0;
            for (; j + 8 <= er; j += 8) {
                int u0 = __shfl(nb, j + sub, 64);
                int u1 = __shfl(nb, j + 2 + sub, 64);
                int u2 = __shfl(nb, j + 4 + sub, 64);
                int u3 = __shfl(nb, j + 6 + sub, 64);
                float2 x0 = __half22float2(g2h[(u0 << 5) + f2]);
                float2 x1 = __half22float2(g2h[(u1 << 5) + f2]);
                float2 x2 = __half22float2(g2h[(u2 << 5) + f2]);
                float2 x3 = __half22float2(g2h[(u3 << 5) + f2]);
                ax += (x0.x + x1.x) + (x2.x + x3.x);
                ay += (x0.y + x1.y) + (x2.y + x3.y);
            }
            for (; j < er; j += 2) {
                int idx = j + sub;
                int u = __shfl(nb, idx < er ? idx : 0, 64);
                float2 xv = __half22float2(g2h[(u << 5) + f2]);
                if (idx < er) { ax += xv.x; ay += xv.y; }
            }
        }
        // reduce over sub -> all lanes hold totals for features (2*f2, 2*f2+1)
        ax += __shfl_xor(ax, 32, 64);
        ay += __shfl_xor(ay, 32, 64);
        float dv = dinv[v];
        float2 sv = __half22float2(g2h[(v << 5) + f2]);
        float a2x = dv * (ax + sv.x);
        float a2y = dv * (ay + sv.y);
        // gemm2: s = b2[lane] + sum_k a2[k] * W2[k][lane]; pair k from lane k>>1
        float s = bs[lane];
#pragma unroll
        for (int k = 0; k < H; k += 2) {
            float vx = __shfl(a2x, k >> 1, 64);
            float vy = __shfl(a2y, k >> 1, 64);
            s += vx * Ws[k * H + lane] + vy * Ws[(k + 1) * H + lane];
        }
        h2[(v << 6) + lane] = tanhf(s);
    }
}

// ================================================================ FC head
// grid: 128 kchunks (1024 k) x 4 graph-groups (8 graphs) = 512 blocks x 256 thr.
__global__ __launch_bounds__(256) void fc_kernel(const float* __restrict__ h2,
                                                 const float* __restrict__ Wfc,
                                                 float* __restrict__ out) {
    int kc = blockIdx.x & 127;
    int gg = blockIdx.x >> 7;
    int t  = threadIdx.x;
    float acc[8][12];
#pragma unroll
    for (int g = 0; g < 8; g++)
#pragma unroll
        for (int j = 0; j < OUT_F; j++) acc[g][j] = 0.f;
    const float* hbase = h2 + (size_t)gg * 8 * KPG;
#pragma unroll
    for (int i = 0; i < 4; i++) {
        int k = (kc << 10) + (i << 8) + t;
        const float4* w4 = (const float4*)(Wfc + (size_t)k * OUT_F);
        float4 w0 = w4[0], w1 = w4[1], w2 = w4[2];
        float hv[8];
#pragma unroll
        for (int g = 0; g < 8; g++) hv[g] = hbase[(size_t)g * KPG + k];
#pragma unroll
        for (int g = 0; g < 8; g++) {
            acc[g][0] += hv[g] * w0.x;  acc[g][1] += hv[g] * w0.y;
            acc[g][2] += hv[g] * w0.z;  acc[g][3] += hv[g] * w0.w;
            acc[g][4] += hv[g] * w1.x;  acc[g][5] += hv[g] * w1.y;
            acc[g][6] += hv[g] * w1.z;  acc[g][7] += hv[g] * w1.w;
            acc[g][8] += hv[g] * w2.x;  acc[g][9] += hv[g] * w2.y;
            acc[g][10] += hv[g] * w2.z; acc[g][11] += hv[g] * w2.w;
        }
    }
#pragma unroll
    for (int g = 0; g < 8; g++)
#pragma unroll
        for (int j = 0; j < OUT_F; j++) {
            float v = acc[g][j];
            v += __shfl_xor(v, 1, 64);  v += __shfl_xor(v, 2, 64);
            v += __shfl_xor(v, 4, 64);  v += __shfl_xor(v, 8, 64);
            v += __shfl_xor(v, 16, 64); v += __shfl_xor(v, 32, 64);
            acc[g][j] = v;
        }
    __shared__ float red[4][96];
    int w = t >> 6;
    if ((t & 63) == 0) {
#pragma unroll
        for (int g = 0; g < 8; g++)
#pragma unroll
            for (int j = 0; j < OUT_F; j++) red[w][g * OUT_F + j] = acc[g][j];
    }
    __syncthreads();
    if (t < 96)
        atomicAdd(&out[gg * 96 + t], red[0][t] + red[1][t] + red[2][t] + red[3][t]);
}

// ================================================================ launcher
extern "C" void kernel_launch(void* const* d_in, const int* in_sizes, int n_in,
                              void* d_out, int out_size, void* d_ws, size_t ws_size,
                              hipStream_t stream) {
    const float* x    = (const float*)d_in[0];
    const int*   edge = (const int*)d_in[1];
    const int*   src  = edge;
    const int*   dst  = edge + N_EDGES;
    const float* W1  = (const float*)d_in[3];
    const float* b1  = (const float*)d_in[4];
    const float* W2  = (const float*)d_in[5];
    const float* b2  = (const float*)d_in[6];
    const float* Wfc = (const float*)d_in[7];
    const float* bfc = (const float*)d_in[8];
    float* out = (float*)d_out;

    char* p = (char*)d_ws;
    auto alloc = [&](size_t n) { char* r = p; p += (n + 255) & ~(size_t)255; return r; };
    int*   blockHist  = (int*)alloc(256 * 256 * 4);
    int*   bucketBase = (int*)alloc(257 * 4);
    int*   gCursor    = (int*)alloc(256 * 4);
    int*   rowptr     = (int*)alloc((N_NODES + 1) * 4);
    float* dinv       = (float*)alloc(N_NODES * 4);
    unsigned short* nbr = (unsigned short*)alloc(N_EDGES * 2 + 256); // pad: agg reads up to +63
    __half* g1h       = (__half*)alloc((size_t)N_NODES * F_IN * 2);
    __half* g2h       = (__half*)alloc((size_t)N_NODES * H * 2);
    float* h2         = (float*)alloc((size_t)N_NODES * H * 4);
    unsigned int* binned = (unsigned int*)alloc((size_t)N_EDGES * 4);

    bucket_count_kernel<<<256, 256, 0, stream>>>(dst, blockHist);
    scan_buckets_kernel<<<1, 256, 0, stream>>>(blockHist, bucketBase, gCursor, bfc, out);
    binA_kernel<<<256, 256, 0, stream>>>(src, dst, gCursor, binned);
    binB_g1_kernel<<<256, 256, 0, stream>>>(binned, bucketBase, x, rowptr, dinv, nbr,
                                            (__half2*)g1h);
    agg1gemm1_kernel<<<4096, 256, 0, stream>>>((const __half2*)g1h, rowptr, nbr, dinv,
                                               W1, b1, g2h);
    agg2gemm2_kernel<<<4096, 256, 0, stream>>>((const __half2*)g2h, rowptr, nbr, dinv,
                                               W2, b2, h2);
    fc_kernel<<<512, 256, 0, stream>>>(h2, Wfc, out);
}

// Round 8
// 237.839 us; speedup vs baseline: 1.0120x; 1.0120x over previous
//
#include <hip/hip_runtime.h>
#include <hip/hip_fp16.h>

#define N_NODES 65536
#define N_EDGES 1048576
#define F_IN    16
#define H       64
#define N_GRAPHS 32
#define NPG     2048
#define OUT_F   12
#define KPG     (NPG * H)   // 131072 per-graph K for FC

// ================================================================ CSR build
// Edges pack into uint32: src (16b) | dst (16b) << 16.
// Bucket = dst>>8 (256 buckets of 256 nodes). Two-level LDS counting sort.

// 256 blocks x 4096 edges: per-block histogram -> blockHist[blk][bucket] (no atomics/memset)
__global__ __launch_bounds__(256) void bucket_count_kernel(const int* __restrict__ dst,
                                                           int* __restrict__ blockHist) {
    __shared__ int h[256];
    int t = threadIdx.x;
    h[t] = 0;
    __syncthreads();
    int base = blockIdx.x * 4096;
#pragma unroll
    for (int i = 0; i < 16; i++) {
        int d = dst[base + i * 256 + t];
        atomicAdd(&h[d >> 8], 1);
    }
    __syncthreads();
    blockHist[blockIdx.x * 256 + t] = h[t];
}

// 1 block: sum per-block hists, scan -> bucketBase[257], init gCursor; bias-init out
__global__ __launch_bounds__(256) void scan_buckets_kernel(const int* __restrict__ blockHist,
                                                           int* __restrict__ bucketBase,
                                                           int* __restrict__ gCursor,
                                                           const float* __restrict__ bfc,
                                                           float* __restrict__ out) {
    int t = threadIdx.x;
    __shared__ int sc[256];
    int c = 0;
    for (int i = 0; i < 256; i++) c += blockHist[i * 256 + t];
    sc[t] = c;
    __syncthreads();
    for (int off = 1; off < 256; off <<= 1) {
        int v = (t >= off) ? sc[t - off] : 0;
        __syncthreads();
        sc[t] += v;
        __syncthreads();
    }
    int excl = sc[t] - c;
    bucketBase[t] = excl;
    gCursor[t]    = excl;
    if (t == 255) bucketBase[256] = N_EDGES;
    for (int i = t; i < N_GRAPHS * OUT_F; i += 256) out[i] = bfc[i % OUT_F];
}

// 256 blocks x 4096 edges: LDS-staged bin by dst>>8, coalesced flush into bucket regions
__global__ __launch_bounds__(256) void binA_kernel(const int* __restrict__ src,
                                                   const int* __restrict__ dst,
                                                   int* __restrict__ gCursor,
                                                   unsigned int* __restrict__ binned) {
    __shared__ int hist[256];
    __shared__ int sc[256];
    __shared__ int bnd[257];
    __shared__ int lcur[256];
    __shared__ int blkBase[256];
    __shared__ unsigned int staged[4096];
    int t = threadIdx.x;
    hist[t] = 0; lcur[t] = 0;
    __syncthreads();
    int e0 = blockIdx.x * 4096;
    unsigned int rec[16];
#pragma unroll
    for (int i = 0; i < 16; i++) {
        int e = e0 + i * 256 + t;
        unsigned int s = (unsigned int)src[e];
        unsigned int d = (unsigned int)dst[e];
        rec[i] = s | (d << 16);
        atomicAdd(&hist[d >> 8], 1);
    }
    __syncthreads();
    int cnt = hist[t];
    if (cnt) blkBase[t] = atomicAdd(&gCursor[t], cnt);
    sc[t] = cnt;
    __syncthreads();
    for (int off = 1; off < 256; off <<= 1) {
        int v = (t >= off) ? sc[t - off] : 0;
        __syncthreads();
        sc[t] += v;
        __syncthreads();
    }
    bnd[t] = sc[t] - cnt;
    if (t == 255) bnd[256] = 4096;
    __syncthreads();
#pragma unroll
    for (int i = 0; i < 16; i++) {
        int b = rec[i] >> 24;
        int p = bnd[b] + atomicAdd(&lcur[b], 1);
        staged[p] = rec[i];
    }
    __syncthreads();
    for (int i = t; i < 4096; i += 256) {
        int lo = 0;
#pragma unroll
        for (int s = 128; s > 0; s >>= 1)
            if (bnd[lo + s] <= i) lo += s;
        binned[blkBase[lo] + (i - bnd[lo])] = staged[i];
    }
}

// block per bucket: counting sort -> nbr (ushort), rowptr, dinv; PLUS fused g1h write
__global__ __launch_bounds__(256) void binB_g1_kernel(const unsigned int* __restrict__ binned,
                                                      const int* __restrict__ bucketBase,
                                                      const float* __restrict__ x,
                                                      int* __restrict__ rowptr,
                                                      float* __restrict__ dinv,
                                                      unsigned short* __restrict__ nbr,
                                                      __half2* __restrict__ g1h) {
    __shared__ int hist[256];
    __shared__ int sc[256];
    __shared__ int off[256];
    __shared__ int cur[256];
    __shared__ unsigned short outS[8192];
    int b = blockIdx.x, t = threadIdx.x;
    int base = bucketBase[b];
    int cnt  = bucketBase[b + 1] - base;
    hist[t] = 0; cur[t] = 0;
    __syncthreads();
    for (int i = t; i < cnt; i += 256) {
        unsigned int r = binned[base + i];
        atomicAdd(&hist[(r >> 16) & 255], 1);
    }
    __syncthreads();
    int c = hist[t];
    sc[t] = c;
    __syncthreads();
    for (int o = 1; o < 256; o <<= 1) {
        int v = (t >= o) ? sc[t - o] : 0;
        __syncthreads();
        sc[t] += v;
        __syncthreads();
    }
    off[t] = sc[t] - c;
    int nd = (b << 8) + t;
    float dv = rsqrtf((float)(c + 1));
    rowptr[nd] = base + sc[t] - c;
    dinv[nd]   = dv;
    if (b == 255 && t == 255) rowptr[N_NODES] = N_EDGES;
    {
        const float4* xr = (const float4*)(x + (size_t)nd * F_IN);
        float4 x0 = xr[0], x1 = xr[1], x2 = xr[2], x3 = xr[3];
        __half2* gr = g1h + nd * 8;
        gr[0] = __floats2half2_rn(x0.x * dv, x0.y * dv);
        gr[1] = __floats2half2_rn(x0.z * dv, x0.w * dv);
        gr[2] = __floats2half2_rn(x1.x * dv, x1.y * dv);
        gr[3] = __floats2half2_rn(x1.z * dv, x1.w * dv);
        gr[4] = __floats2half2_rn(x2.x * dv, x2.y * dv);
        gr[5] = __floats2half2_rn(x2.z * dv, x2.w * dv);
        gr[6] = __floats2half2_rn(x3.x * dv, x3.y * dv);
        gr[7] = __floats2half2_rn(x3.z * dv, x3.w * dv);
    }
    __syncthreads();
    for (int i = t; i < cnt; i += 256) {
        unsigned int r = binned[base + i];
        int n = (r >> 16) & 255;
        int p = off[n] + atomicAdd(&cur[n], 1);
        outS[p] = (unsigned short)(r & 0xFFFF);
    }
    __syncthreads();
    for (int i = t; i < cnt; i += 256) nbr[base + i] = outS[i];
}

// ================================================================ layer 1
// a1[v] = dinv[v]*(g1[v] + sum g1[u]); wave per node, 8 edges/round (R5 structure)
__global__ __launch_bounds__(256) void agg1_kernel(const __half2* __restrict__ g1h,
                                                   const int* __restrict__ rowptr,
                                                   const unsigned short* __restrict__ nbr,
                                                   const float* __restrict__ dinv,
                                                   float2* __restrict__ a1) {
    int v    = (blockIdx.x * blockDim.x + threadIdx.x) >> 6;
    int lane = threadIdx.x & 63;
    int f2   = lane & 7;
    int sub  = lane >> 3;
    int r0 = rowptr[v], r1 = rowptr[v + 1];
    float ax = 0.f, ay = 0.f;
    for (int base = r0; base < r1; base += 64) {
        int er = min(64, r1 - base);
        int nb = (int)nbr[base + lane];
        int j = 0;
        for (; j + 16 <= er; j += 16) {
            int u0 = __shfl(nb, j + sub, 64);
            int u1 = __shfl(nb, j + 8 + sub, 64);
            float2 x0 = __half22float2(g1h[(u0 << 3) + f2]);
            float2 x1 = __half22float2(g1h[(u1 << 3) + f2]);
            ax += x0.x + x1.x;
            ay += x0.y + x1.y;
        }
        for (; j < er; j += 8) {
            int idx = j + sub;
            int u = __shfl(nb, idx < er ? idx : 0, 64);
            float2 xv = __half22float2(g1h[(u << 3) + f2]);
            if (idx < er) { ax += xv.x; ay += xv.y; }
        }
    }
    ax += __shfl_xor(ax, 8, 64);  ax += __shfl_xor(ax, 16, 64);  ax += __shfl_xor(ax, 32, 64);
    ay += __shfl_xor(ay, 8, 64);  ay += __shfl_xor(ay, 16, 64);  ay += __shfl_xor(ay, 32, 64);
    if (sub == 0) {
        float2 sv = __half22float2(g1h[(v << 3) + f2]);
        float dv = dinv[v];
        a1[(v << 3) + f2] = make_float2(dv * (ax + sv.x), dv * (ay + sv.y));
    }
}

// g2h[v] = fp16( dinv[v] * tanh(a1[v] @ W1 + b1) )
__global__ void gemm1_kernel(const float* __restrict__ a1, const float* __restrict__ W1,
                             const float* __restrict__ b1, const float* __restrict__ dinv,
                             __half* __restrict__ g2h) {
    __shared__ float Ws[F_IN * H];
    __shared__ float bs[H];
    __shared__ float As[4][F_IN];
    int t = threadIdx.x;
    for (int i = t; i < F_IN * H; i += 256) Ws[i] = W1[i];
    if (t < H) bs[t] = b1[t];
    int sub = t >> 6, f = t & 63;
    int v   = blockIdx.x * 4 + sub;
    if (f < F_IN) As[sub][f] = a1[v * F_IN + f];
    __syncthreads();
    float s = bs[f];
#pragma unroll
    for (int k = 0; k < F_IN; k++) s += As[sub][k] * Ws[k * H + f];
    g2h[(v << 6) + f] = __float2half(dinv[v] * tanhf(s));
}

// ================================================================ layer 2
// a2[v] = dinv[v]*(g2[v] + sum g2[u]); wave per node, 2 edges/round x4 (R5 structure)
__global__ __launch_bounds__(256) void agg2_kernel(const __half2* __restrict__ g2h,
                                                   const int* __restrict__ rowptr,
                                                   const unsigned short* __restrict__ nbr,
                                                   const float* __restrict__ dinv,
                                                   float2* __restrict__ a2) {
    int v    = (blockIdx.x * blockDim.x + threadIdx.x) >> 6;
    int lane = threadIdx.x & 63;
    int f2   = lane & 31;
    int sub  = lane >> 5;
    int r0 = rowptr[v], r1 = rowptr[v + 1];
    float ax = 0.f, ay = 0.f;
    for (int base = r0; base < r1; base += 64) {
        int er = min(64, r1 - base);
        int nb = (int)nbr[base + lane];
        int j = 0;
        for (; j + 8 <= er; j += 8) {
            int u0 = __shfl(nb, j + sub, 64);
            int u1 = __shfl(nb, j + 2 + sub, 64);
            int u2 = __shfl(nb, j + 4 + sub, 64);
            int u3 = __shfl(nb, j + 6 + sub, 64);
            float2 x0 = __half22float2(g2h[(u0 << 5) + f2]);
            float2 x1 = __half22float2(g2h[(u1 << 5) + f2]);
            float2 x2 = __half22float2(g2h[(u2 << 5) + f2]);
            float2 x3 = __half22float2(g2h[(u3 << 5) + f2]);
            ax += (x0.x + x1.x) + (x2.x + x3.x);
            ay += (x0.y + x1.y) + (x2.y + x3.y);
        }
        for (; j < er; j += 2) {
            int idx = j + sub;
            int u = __shfl(nb, idx < er ? idx : 0, 64);
            float2 xv = __half22float2(g2h[(u << 5) + f2]);
            if (idx < er) { ax += xv.x; ay += xv.y; }
        }
    }
    ax += __shfl_xor(ax, 32, 64);
    ay += __shfl_xor(ay, 32, 64);
    if (sub == 0) {
        float2 sv = __half22float2(g2h[(v << 5) + f2]);
        float dv = dinv[v];
        a2[(v << 5) + f2] = make_float2(dv * (ax + sv.x), dv * (ay + sv.y));
    }
}

// h2[v] = tanh(a2[v] @ W2 + b2)
__global__ void gemm2_kernel(const float* __restrict__ a2, const float* __restrict__ W2,
                             const float* __restrict__ b2, float* __restrict__ h2) {
    __shared__ float Ws[H * H];
    __shared__ float bs[H];
    __shared__ float As[4][H];
    int t = threadIdx.x;
    for (int i = t; i < H * H; i += 256) Ws[i] = W2[i];
    if (t < H) bs[t] = b2[t];
    int sub = t >> 6, f = t & 63;
    int v   = blockIdx.x * 4 + sub;
    As[sub][f] = a2[(v << 6) + f];
    __syncthreads();
    float s = bs[f];
#pragma unroll
    for (int k = 0; k < H; k++) s += As[sub][k] * Ws[k * H + f];
    h2[(v << 6) + f] = tanhf(s);
}

// ================================================================ FC head
// grid: 128 kchunks (1024 k) x 4 graph-groups (8 graphs) = 512 blocks x 256 thr.
__global__ __launch_bounds__(256) void fc_kernel(const float* __restrict__ h2,
                                                 const float* __restrict__ Wfc,
                                                 float* __restrict__ out) {
    int kc = blockIdx.x & 127;
    int gg = blockIdx.x >> 7;
    int t  = threadIdx.x;
    float acc[8][12];
#pragma unroll
    for (int g = 0; g < 8; g++)
#pragma unroll
        for (int j = 0; j < OUT_F; j++) acc[g][j] = 0.f;
    const float* hbase = h2 + (size_t)gg * 8 * KPG;
#pragma unroll
    for (int i = 0; i < 4; i++) {
        int k = (kc << 10) + (i << 8) + t;
        const float4* w4 = (const float4*)(Wfc + (size_t)k * OUT_F);
        float4 w0 = w4[0], w1 = w4[1], w2 = w4[2];
        float hv[8];
#pragma unroll
        for (int g = 0; g < 8; g++) hv[g] = hbase[(size_t)g * KPG + k];
#pragma unroll
        for (int g = 0; g < 8; g++) {
            acc[g][0] += hv[g] * w0.x;  acc[g][1] += hv[g] * w0.y;
            acc[g][2] += hv[g] * w0.z;  acc[g][3] += hv[g] * w0.w;
            acc[g][4] += hv[g] * w1.x;  acc[g][5] += hv[g] * w1.y;
            acc[g][6] += hv[g] * w1.z;  acc[g][7] += hv[g] * w1.w;
            acc[g][8] += hv[g] * w2.x;  acc[g][9] += hv[g] * w2.y;
            acc[g][10] += hv[g] * w2.z; acc[g][11] += hv[g] * w2.w;
        }
    }
#pragma unroll
    for (int g = 0; g < 8; g++)
#pragma unroll
        for (int j = 0; j < OUT_F; j++) {
            float v = acc[g][j];
            v += __shfl_xor(v, 1, 64);  v += __shfl_xor(v, 2, 64);
            v += __shfl_xor(v, 4, 64);  v += __shfl_xor(v, 8, 64);
            v += __shfl_xor(v, 16, 64); v += __shfl_xor(v, 32, 64);
            acc[g][j] = v;
        }
    __shared__ float red[4][96];
    int w = t >> 6;
    if ((t & 63) == 0) {
#pragma unroll
        for (int g = 0; g < 8; g++)
#pragma unroll
            for (int j = 0; j < OUT_F; j++) red[w][g * OUT_F + j] = acc[g][j];
    }
    __syncthreads();
    if (t < 96)
        atomicAdd(&out[gg * 96 + t], red[0][t] + red[1][t] + red[2][t] + red[3][t]);
}

// ================================================================ launcher
extern "C" void kernel_launch(void* const* d_in, const int* in_sizes, int n_in,
                              void* d_out, int out_size, void* d_ws, size_t ws_size,
                              hipStream_t stream) {
    const float* x    = (const float*)d_in[0];
    const int*   edge = (const int*)d_in[1];
    const int*   src  = edge;
    const int*   dst  = edge + N_EDGES;
    const float* W1  = (const float*)d_in[3];
    const float* b1  = (const float*)d_in[4];
    const float* W2  = (const float*)d_in[5];
    const float* b2  = (const float*)d_in[6];
    const float* Wfc = (const float*)d_in[7];
    const float* bfc = (const float*)d_in[8];
    float* out = (float*)d_out;

    char* p = (char*)d_ws;
    auto alloc = [&](size_t n) { char* r = p; p += (n + 255) & ~(size_t)255; return r; };
    int*   blockHist  = (int*)alloc(256 * 256 * 4);
    int*   bucketBase = (int*)alloc(257 * 4);
    int*   gCursor    = (int*)alloc(256 * 4);
    int*   rowptr     = (int*)alloc((N_NODES + 1) * 4);
    float* dinv       = (float*)alloc(N_NODES * 4);
    unsigned short* nbr = (unsigned short*)alloc(N_EDGES * 2 + 256); // pad: agg reads up to +63
    __half* g1h       = (__half*)alloc((size_t)N_NODES * F_IN * 2);
    float* a1         = (float*)alloc((size_t)N_NODES * F_IN * 4);
    __half* g2h       = (__half*)alloc((size_t)N_NODES * H * 2);
    float* a2         = (float*)alloc((size_t)N_NODES * H * 4);
    float* h2         = (float*)alloc((size_t)N_NODES * H * 4);
    unsigned int* binned = (unsigned int*)alloc((size_t)N_EDGES * 4);

    bucket_count_kernel<<<256, 256, 0, stream>>>(dst, blockHist);
    scan_buckets_kernel<<<1, 256, 0, stream>>>(blockHist, bucketBase, gCursor, bfc, out);
    binA_kernel<<<256, 256, 0, stream>>>(src, dst, gCursor, binned);
    binB_g1_kernel<<<256, 256, 0, stream>>>(binned, bucketBase, x, rowptr, dinv, nbr,
                                            (__half2*)g1h);
    agg1_kernel<<<N_NODES / 4, 256, 0, stream>>>((const __half2*)g1h, rowptr, nbr, dinv,
                                                 (float2*)a1);
    gemm1_kernel<<<N_NODES / 4, 256, 0, stream>>>(a1, W1, b1, dinv, g2h);
    agg2_kernel<<<N_NODES / 4, 256, 0, stream>>>((const __half2*)g2h, rowptr, nbr, dinv,
                                                 (float2*)a2);
    gemm2_kernel<<<N_NODES / 4, 256, 0, stream>>>(a2, W2, b2, h2);
    fc_kernel<<<512, 256, 0, stream>>>(h2, Wfc, out);
}